// Round 9
// baseline (486.480 us; speedup 1.0000x reference)
//
#include <hip/hip_runtime.h>
#include <stdint.h>

// ---------------- types / helpers ----------------
typedef short bf16x8 __attribute__((ext_vector_type(8)));
typedef float f32x4 __attribute__((ext_vector_type(4)));
typedef unsigned short u16;
typedef unsigned short u16x4 __attribute__((ext_vector_type(4)));

#define AS1 __attribute__((address_space(1)))
#define AS3 __attribute__((address_space(3)))

__device__ __forceinline__ void gll16(const void* g, void* l) {
  // async global->LDS, 16B per lane, LDS dest = wave-uniform base + lane*16
  __builtin_amdgcn_global_load_lds((const AS1 uint32_t*)g, (AS3 uint32_t*)l, 16, 0, 0);
}

__device__ __forceinline__ f32x4 mfma16(bf16x8 a, bf16x8 b, f32x4 c) {
  return __builtin_amdgcn_mfma_f32_16x16x32_bf16(a, b, c, 0, 0, 0);
}

__device__ __forceinline__ u16 f2bf(float f) {
  union { float f; uint32_t u; } c; c.f = f;
  uint32_t r = c.u + 0x7FFFu + ((c.u >> 16) & 1u);   // RNE
  return (u16)(r >> 16);
}
__device__ __forceinline__ float bf2f(u16 h) {
  union { uint32_t u; float f; } c; c.u = ((uint32_t)h) << 16; return c.f;
}

// ---------------- cast fp32 -> bf16 ----------------
__global__ __launch_bounds__(256) void k_cast(const float* __restrict__ in, u16* __restrict__ out) {
  int i = (blockIdx.x * 256 + threadIdx.x) * 4;
  float4 v = *(const float4*)(in + i);
  u16x4 r; r.x = f2bf(v.x); r.y = f2bf(v.y); r.z = f2bf(v.z); r.w = f2bf(v.w);
  *(u16x4*)(out + i) = r;
}

// ---------------- 4 weight transposes fp32 (1024x1024) -> bf16 transposed, one dispatch ----------------
__global__ __launch_bounds__(1024) void k_transpose4(
    const float* __restrict__ wq, const float* __restrict__ wk,
    const float* __restrict__ wv, const float* __restrict__ wo,
    u16* __restrict__ Wqkvt, u16* __restrict__ Wot) {
  __shared__ float t[32][33];
  const float* src; u16* dst;
  int z = blockIdx.z;
  if (z == 0)      { src = wq; dst = Wqkvt; }
  else if (z == 1) { src = wk; dst = Wqkvt + 1024 * 1024; }
  else if (z == 2) { src = wv; dst = Wqkvt + 2 * 1024 * 1024; }
  else             { src = wo; dst = Wot; }
  int tx = threadIdx.x, ty = threadIdx.y;
  t[ty][tx] = src[(size_t)(blockIdx.y * 32 + ty) * 1024 + blockIdx.x * 32 + tx];
  __syncthreads();
  dst[(size_t)(blockIdx.x * 32 + ty) * 1024 + blockIdx.y * 32 + tx] = f2bf(t[tx][ty]);
}

// ================= 256x256 / BK=64 / 8-wave pipelined main loop =================
// (verified green in round 8: 104.5 us, MfmaUtil 42%, 0 bank conflicts — UNCHANGED)
__device__ __forceinline__ void gemm256_loop(
    const u16* __restrict__ Ag, const u16* __restrict__ Bg,
    u16* lds, int m0, int n0, f32x4 (&acc)[8][4])
{
  const int tid = threadIdx.x, lane = tid & 63, w = tid >> 6;
  const int wm = w >> 2, wn = w & 3;
  const int l8 = lane >> 3, c7 = lane & 7;
  const int mm = lane & 15, quad = lane >> 4;
  const int ch0 = (quad ^ (mm & 7)) * 8;          // phys chunk for ks=0 (u16 offset)
  const int ch1 = ((quad ^ (mm & 7)) ^ 4) * 8;    // phys chunk for ks=1

  const u16* aSt = Ag + (size_t)(m0 + w * 8 + l8) * 1024 + (c7 ^ l8) * 8;
  const u16* bSt = Bg + (size_t)(n0 + w * 8 + l8) * 1024 + (c7 ^ l8) * 8;
  u16* ldsAw = lds + w * 512;
  u16* ldsBw = lds + 32768 + w * 512;
  const u16* aR0 = lds + (wm * 128 + mm) * 64 + ch0;
  const u16* aR1 = lds + (wm * 128 + mm) * 64 + ch1;
  const u16* bR0 = lds + 32768 + (wn * 64 + mm) * 64 + ch0;
  const u16* bR1 = lds + 32768 + (wn * 64 + mm) * 64 + ch1;

#define STA(q, kt, buf) gll16(aSt + (q) * 65536 + (kt) * 64, ldsAw + (buf) * 16384 + (q) * 4096)
#define STB(q, kt, buf) gll16(bSt + (q) * 65536 + (kt) * 64, ldsBw + (buf) * 16384 + (q) * 4096)

#define LDA(C, MH) do {                                                                  \
    _Pragma("unroll")                                                                    \
    for (int i = 0; i < 4; ++i) {                                                        \
      af[i][0] = *(const bf16x8*)(aR0 + (C) * 16384 + ((MH) * 64 + i * 16) * 64);        \
      af[i][1] = *(const bf16x8*)(aR1 + (C) * 16384 + ((MH) * 64 + i * 16) * 64);        \
    }                                                                                    \
  } while (0)
#define LDBv(C, NH, DST) do {                                                            \
    _Pragma("unroll")                                                                    \
    for (int j = 0; j < 2; ++j) {                                                        \
      DST[j][0] = *(const bf16x8*)(bR0 + (C) * 16384 + ((NH) * 32 + j * 16) * 64);       \
      DST[j][1] = *(const bf16x8*)(bR1 + (C) * 16384 + ((NH) * 32 + j * 16) * 64);       \
    }                                                                                    \
  } while (0)
#define MM(MH, NH, BF) do {                                                              \
    __builtin_amdgcn_s_setprio(1);                                                       \
    _Pragma("unroll")                                                                    \
    for (int ks = 0; ks < 2; ++ks)                                                       \
      _Pragma("unroll")                                                                  \
      for (int i = 0; i < 4; ++i)                                                        \
        _Pragma("unroll")                                                                \
        for (int j = 0; j < 2; ++j)                                                      \
          acc[(MH) * 4 + i][(NH) * 2 + j] =                                              \
              mfma16(af[i][ks], BF[j][ks], acc[(MH) * 4 + i][(NH) * 2 + j]);             \
    __builtin_amdgcn_s_setprio(0);                                                       \
  } while (0)

// one K-tile: TT = tile index (runtime), C = LDS buffer (compile-time 0/1)
#define TILE(TT, C) do {                                                                 \
    const int t1 = (TT) + 1, t2 = (TT) + 2;                                              \
    const bool sB = t1 < 16, sA = t2 < 16;                                               \
    /* ph0 */                                                                            \
    LDA(C, 0); LDBv(C, 0, bfA);                                                          \
    __builtin_amdgcn_sched_barrier(0);    /* pin: bfB issues AFTER af(MH0)+bfA */        \
    LDBv(C, 1, bfB);                                                                     \
    __builtin_amdgcn_sched_barrier(0);                                                   \
    if (sB) { STB(0, t1, 1 - (C)); STB(1, t1, 1 - (C)); }                                \
    asm volatile("s_waitcnt lgkmcnt(4)" ::: "memory");  /* af(MH0)+bfA done */           \
    __builtin_amdgcn_sched_barrier(0);                                                   \
    MM(0, 0, bfA);                                                                       \
    /* ph1 (af untouched: MM(0,1) still needs MH0) */                                    \
    if (sB) { STB(2, t1, 1 - (C)); STB(3, t1, 1 - (C)); }                                \
    asm volatile("s_waitcnt lgkmcnt(0)" ::: "memory");  /* bfB done (hidden) */          \
    __builtin_amdgcn_sched_barrier(0);                                                   \
    MM(0, 1, bfB);                                                                       \
    /* ph2 */                                                                            \
    LDA(C, 1);                              /* af MH1; MH0 dead after MM(0,1) */         \
    __builtin_amdgcn_sched_barrier(0);                                                   \
    asm volatile("s_waitcnt lgkmcnt(0)" ::: "memory");  /* af(MH1) done */               \
    __builtin_amdgcn_sched_barrier(0);                                                   \
    MM(1, 1, bfB);                                                                       \
    __builtin_amdgcn_s_barrier();                              /* B2 */                  \
    /* ph3 */                                                                            \
    if (sA) { STA(0, t2, C); STA(1, t2, C); STA(2, t2, C); STA(3, t2, C); }              \
    MM(1, 0, bfA);                                                                       \
    if ((TT) < 14)       asm volatile("s_waitcnt vmcnt(4)" ::: "memory");                \
    else if ((TT) == 14) asm volatile("s_waitcnt vmcnt(0)" ::: "memory");                \
    __builtin_amdgcn_s_barrier();                              /* B3 */                  \
  } while (0)

#pragma unroll
  for (int i = 0; i < 8; ++i)
#pragma unroll
    for (int j = 0; j < 4; ++j) acc[i][j] = (f32x4){0.f, 0.f, 0.f, 0.f};

  // prologue: A,B of tile 0 -> buf0; all of A of tile 1 -> buf1 (stays in flight)
  STA(0, 0, 0); STA(1, 0, 0); STA(2, 0, 0); STA(3, 0, 0);
  STB(0, 0, 0); STB(1, 0, 0); STB(2, 0, 0); STB(3, 0, 0);
  STA(0, 1, 1); STA(1, 1, 1); STA(2, 1, 1); STA(3, 1, 1);
  asm volatile("s_waitcnt vmcnt(4)" ::: "memory");
  __builtin_amdgcn_s_barrier();

#pragma unroll 1
  for (int t = 0; t < 16; t += 2) {
    bf16x8 af[4][2]; bf16x8 bfA[2][2]; bf16x8 bfB[2][2];
    TILE(t, 0);
    TILE(t + 1, 1);
  }
#undef TILE
#undef MM
#undef LDA
#undef LDBv
#undef STA
#undef STB
}

// ---------------- fused QKV GEMM: A[16384x1024] * Wqkvt[3072x1024]^T ----------------
// 256x256 tile, 512 threads, 128 KiB LDS, 1 block/CU. XCD-chunked block swizzle (768=8*96).
__global__ __launch_bounds__(512, 2) void k_gemm_qkv(
    const u16* __restrict__ A, const u16* __restrict__ Bt,
    const float* __restrict__ bq, const float* __restrict__ bk, const float* __restrict__ bv,
    u16* __restrict__ Qb, u16* __restrict__ Kb, u16* __restrict__ Vbt, float* __restrict__ sumk)
{
  __shared__ __align__(16) u16 LDS[65536];   // 128 KiB
  int lin = blockIdx.x + 12 * blockIdx.y;          // 0..767
  int nb = (lin & 7) * 96 + (lin >> 3);            // bijective XCD chunking
  const int m0 = (nb / 12) * 256, n0 = (nb % 12) * 256;
  f32x4 acc[8][4];
  gemm256_loop(A, Bt, LDS, m0, n0, acc);

  const int tid = threadIdx.x, lane = tid & 63, w = tid >> 6;
  const int wm = w >> 2, wn = w & 3;
  const int mm = lane & 15, quad = lane >> 4;
  const int sel = n0 >> 10;                   // 0=Q, 1=K, 2=V (uniform per block)
  const float* bias = sel == 0 ? bq : (sel == 1 ? bk : bv);
  // NOTE: all waves are past the loop's final barrier -> LDS free; each wave uses only
  // its own 16KB region below (no cross-wave traffic, no further barriers needed).
  u16* W = LDS + w * 8192;

  if (sel == 2) {
    // ---- V epilogue: per-wave LDS transpose, then coalesced d-major 8B stores ----
#pragma unroll
    for (int nf = 0; nf < 4; ++nf) {
      int d = nf * 16 + mm;
      float bval = bias[((n0 & 1023) + wn * 64 + nf * 16 + mm)];
#pragma unroll
      for (int mf = 0; mf < 8; ++mf) {
        int c = mf * 4 + quad;
        u16x4 pk;
        pk.x = f2bf(acc[mf][nf][0] + bval);
        pk.y = f2bf(acc[mf][nf][1] + bval);
        pk.z = f2bf(acc[mf][nf][2] + bval);
        pk.w = f2bf(acc[mf][nf][3] + bval);
        *(u16x4*)(W + d * 128 + (c ^ (d & 15)) * 4) = pk;
      }
    }
    asm volatile("s_waitcnt lgkmcnt(0)" ::: "memory");
    int h_w = ((n0 & 1023) >> 6) + wn;
    int b_ = m0 >> 12;
    int c = lane & 31, dpar = lane >> 5;
    size_t gbase = ((size_t)(b_ * 16 + h_w) * 64) * 4096 + (m0 & 4095) + wm * 128 + c * 4;
#pragma unroll
    for (int dd = 0; dd < 32; ++dd) {
      int d = dd * 2 + dpar;
      u16x4 v = *(const u16x4*)(W + d * 128 + (c ^ (d & 15)) * 4);
      *(u16x4*)(Vbt + gbase + (size_t)d * 4096) = v;
    }
    return;
  }

  // ---- Q/K epilogue: per-wave LDS re-tile [128s][64d] with chunk swizzle
  //      k(s)=(s^(s>>3))&7 (breaks the 8-way row-aliased write conflict), then
  //      16B/lane linear stores ----
  const float scl = sel == 0 ? 0.125f : 1.0f;
#pragma unroll
  for (int nf = 0; nf < 4; ++nf) {
    float bval = bias[(n0 & 1023) + wn * 64 + nf * 16 + mm];
    int d = nf * 16 + mm;
    int dc = d >> 3, dw = d & 7;
#pragma unroll
    for (int mf = 0; mf < 8; ++mf)
#pragma unroll
      for (int r = 0; r < 4; ++r) {
        int s = mf * 16 + quad * 4 + r;
        int kk = (s ^ (s >> 3)) & 7;
        W[s * 64 + ((dc ^ kk) << 3) + dw] = f2bf((acc[mf][nf][r] + bval) * scl);
      }
  }
  asm volatile("s_waitcnt lgkmcnt(0)" ::: "memory");
  {
    int h = ((n0 & 1023) >> 6) + wn;
    int mg0 = m0 + wm * 128;
    int b_ = mg0 >> 12;
    u16* dst = (sel == 0 ? Qb : Kb) + ((size_t)(b_ * 16 + h) * 4096 + (mg0 & 4095)) * 64;
    int l8 = lane >> 3, c8 = lane & 7;
#pragma unroll
    for (int i = 0; i < 16; ++i) {
      int s = i * 8 + l8;
      int kk = (l8 ^ i) & 7;
      *(bf16x8*)(dst + s * 64 + c8 * 8) = *(const bf16x8*)(W + s * 64 + ((c8 ^ kk) << 3));
    }
  }

  if (sel == 1) {
    // per-wave: wave (wm,wn) covers rows [m0+wm*128, +128) x cols [wn*64, +64)
    // -> exactly one sumk block (nb = m0/128 + wm) per wave, no cross-wave reduction.
#pragma unroll
    for (int nf = 0; nf < 4; ++nf) {
      float ssum = 0.f;
#pragma unroll
      for (int mf = 0; mf < 8; ++mf)
#pragma unroll
        for (int r = 0; r < 4; ++r) ssum += acc[mf][nf][r];
      ssum += __shfl_xor(ssum, 16);
      ssum += __shfl_xor(ssum, 32);            // sum over the 4 quads -> 128 rows
      if (quad == 0) {
        int colg = (n0 - 1024) + wn * 64 + nf * 16 + mm;
        int b_ = m0 >> 12, nb2 = ((m0 >> 7) & 31) + wm;
        sumk[(size_t)(b_ * 32 + nb2) * 1024 + colg] = ssum + 128.f * bias[colg];
      }
    }
  }
}

// ---------------- output GEMM: X[16384x1024] * Wot[1024x1024]^T + bo -> fp32 ----------------
__global__ __launch_bounds__(512, 2) void k_gemm_out(
    const u16* __restrict__ A, const u16* __restrict__ Bt,
    const float* __restrict__ bo, float* __restrict__ out)
{
  __shared__ __align__(16) u16 LDS[65536];   // 128 KiB
  int lin = blockIdx.x + 4 * blockIdx.y;           // 0..255
  int nb = (lin & 7) * 32 + (lin >> 3);            // bijective XCD chunking
  const int m0 = (nb / 4) * 256, n0 = (nb % 4) * 256;
  f32x4 acc[8][4];
  gemm256_loop(A, Bt, LDS, m0, n0, acc);

  const int tid = threadIdx.x, lane = tid & 63, w = tid >> 6;
  const int wm = w >> 2, wn = w & 3;
  const int mm = lane & 15, quad = lane >> 4;
#pragma unroll
  for (int nf = 0; nf < 4; ++nf) {
    int ng = n0 + wn * 64 + nf * 16 + mm;
    float bval = bo[ng];
#pragma unroll
    for (int mf = 0; mf < 8; ++mf)
#pragma unroll
      for (int r = 0; r < 4; ++r) {
        int mg = m0 + wm * 128 + mf * 16 + quad * 4 + r;
        out[(size_t)mg * 1024 + ng] = acc[mf][nf][r] + bval;
      }
  }
}

// ---------------- merged sort logits + Sinkhorn (one dispatch, 4 blocks) ----------------
// Phase 1: so[n][m] = sumk[b][n][:] @ wsort[:][m] + bsort[m]  (256 thr: t -> n=t>>3, 4 m's)
// Phase 2: 5 Sinkhorn iterations on A[32][33] in LDS (t<32 active, barriers uniform)
// Phase 3: perm = exp(clip(A, -1, 1))
__global__ __launch_bounds__(256) void k_sortsink(
    const float* __restrict__ sumk, const float* __restrict__ wsort,
    const float* __restrict__ bsort, float* __restrict__ perm) {
  __shared__ float A[32][33];
  int b = blockIdx.x, t = threadIdx.x;
  {
    int n = t >> 3, mg = t & 7;
    const float* row = sumk + (size_t)(b * 32 + n) * 1024;
    float a0 = 0.f, a1 = 0.f, a2 = 0.f, a3 = 0.f;
#pragma unroll 4
    for (int c = 0; c < 1024; ++c) {
      float s = row[c];
      float4 w4 = *(const float4*)(wsort + c * 32 + mg * 4);
      a0 += s * w4.x; a1 += s * w4.y; a2 += s * w4.z; a3 += s * w4.w;
    }
    A[n][mg * 4 + 0] = a0 + bsort[mg * 4 + 0];
    A[n][mg * 4 + 1] = a1 + bsort[mg * 4 + 1];
    A[n][mg * 4 + 2] = a2 + bsort[mg * 4 + 2];
    A[n][mg * 4 + 3] = a3 + bsort[mg * 4 + 3];
  }
  __syncthreads();
  for (int it = 0; it < 5; ++it) {
    if (t < 32) { // row LSE (axis=2)
      float mx = -1e30f;
      for (int j = 0; j < 32; ++j) mx = fmaxf(mx, A[t][j]);
      float s = 0.f;
      for (int j = 0; j < 32; ++j) s += __expf(A[t][j] - mx);
      float l = mx + __logf(s);
      for (int j = 0; j < 32; ++j) A[t][j] -= l;
    }
    __syncthreads();
    if (t < 32) { // col LSE (axis=1)
      float mx = -1e30f;
      for (int j = 0; j < 32; ++j) mx = fmaxf(mx, A[j][t]);
      float s = 0.f;
      for (int j = 0; j < 32; ++j) s += __expf(A[j][t] - mx);
      float l = mx + __logf(s);
      for (int j = 0; j < 32; ++j) A[j][t] -= l;
    }
    __syncthreads();
  }
#pragma unroll
  for (int i = 0; i < 4; ++i) {
    int idx = i * 256 + t;
    perm[(size_t)b * 1024 + idx] = __expf(fminf(fmaxf(A[idx >> 5][idx & 31], -1.f), 1.f));
  }
}

// ---------------- merged block mix (u16x4-vectorized): y<16 K-mix, y>=16 V-mix ----------------
// grid (8, 32, 4). K-mix: thread = (ss = xg*16 + t>>4, d4 = (t&15)*4); 512B/wave loads.
// V-mix: thread = (d = xg*8 + t>>5, ss4 = (t&31)*4); 256B/wave loads. 4 outputs/thread.
__global__ __launch_bounds__(256) void k_mix(
    const u16* __restrict__ Kb, const u16* __restrict__ Vbt, const float* __restrict__ perm,
    u16* __restrict__ Ksort, u16* __restrict__ Vsort)
{
  __shared__ float P[32][32];
  int b = blockIdx.z, y = blockIdx.y, xg = blockIdx.x;
  int tid = threadIdx.x;
#pragma unroll
  for (int i = 0; i < 4; ++i) {
    int idx = i * 256 + tid;
    P[idx >> 5][idx & 31] = perm[b * 1024 + idx];
  }
  __syncthreads();
  if (y < 16) {
    // K mix: Ksort[b][h][n][128s][64d] = sum_m perm[n][m] * K[b][h][m*128+s][d]
    int h = y;
    int ss = xg * 16 + (tid >> 4), dq = (tid & 15) * 4;
    const u16* Kg = Kb + (size_t)(b * 16 + h) * 262144;
    float xk[32][4];
#pragma unroll
    for (int m = 0; m < 32; ++m) {
      u16x4 v = *(const u16x4*)(Kg + (size_t)(m * 128 + ss) * 64 + dq);
      xk[m][0] = bf2f(v.x); xk[m][1] = bf2f(v.y); xk[m][2] = bf2f(v.z); xk[m][3] = bf2f(v.w);
    }
    size_t tbase = (size_t)((b * 16 + h) * 32) * 8192;
#pragma unroll 1
    for (int nn = 0; nn < 32; ++nn) {
      float s0 = 0.f, s1 = 0.f, s2 = 0.f, s3 = 0.f;
#pragma unroll
      for (int m = 0; m < 32; ++m) {
        float p = P[nn][m];
        s0 += p * xk[m][0]; s1 += p * xk[m][1]; s2 += p * xk[m][2]; s3 += p * xk[m][3];
      }
      u16x4 o; o.x = f2bf(s0); o.y = f2bf(s1); o.z = f2bf(s2); o.w = f2bf(s3);
      *(u16x4*)(Ksort + tbase + (size_t)nn * 8192 + ss * 64 + dq) = o;
    }
  } else {
    // V mix (transposed): Vsort[b][h][n][64d][128s] from Vbt[b][h][d][s]
    int h = y - 16;
    int d = xg * 8 + (tid >> 5), sq = (tid & 31) * 4;
    const u16* Vg = Vbt + ((size_t)(b * 16 + h) * 64 + d) * 4096;
    float xv[32][4];
#pragma unroll
    for (int m = 0; m < 32; ++m) {
      u16x4 v = *(const u16x4*)(Vg + m * 128 + sq);
      xv[m][0] = bf2f(v.x); xv[m][1] = bf2f(v.y); xv[m][2] = bf2f(v.z); xv[m][3] = bf2f(v.w);
    }
    size_t tbase = (size_t)((b * 16 + h) * 32) * 8192;
#pragma unroll 1
    for (int nn = 0; nn < 32; ++nn) {
      float s0 = 0.f, s1 = 0.f, s2 = 0.f, s3 = 0.f;
#pragma unroll
      for (int m = 0; m < 32; ++m) {
        float p = P[nn][m];
        s0 += p * xv[m][0]; s1 += p * xv[m][1]; s2 += p * xv[m][2]; s3 += p * xv[m][3];
      }
      u16x4 o; o.x = f2bf(s0); o.y = f2bf(s1); o.z = f2bf(s2); o.w = f2bf(s3);
      *(u16x4*)(Vsort + tbase + (size_t)nn * 8192 + d * 128 + sq) = o;
    }
  }
}

// ---------------- attention per (b,n,h): softmax(Q Kcat^T) Vcat ----------------
__global__ __launch_bounds__(256, 2) void k_attn(
    const u16* __restrict__ Qb, const u16* __restrict__ Kb, const u16* __restrict__ Ksort,
    const u16* __restrict__ Vbt, const u16* __restrict__ Vsort, u16* __restrict__ X)
{
  __shared__ u16 Ks[16384];    // 256 kk x 64 d (swizzled); later overlaid by per-wave P
  __shared__ u16 Vlo[8192];    // 64 d x 128 kk (orig half, swizzled)
  __shared__ u16 Vhi[8192];    // 64 d x 128 kk (sorted half, swizzled)
  int tid = threadIdx.x, lane = tid & 63, w = tid >> 6;
  int n = blockIdx.x, h = blockIdx.y, b = blockIdx.z;
  size_t bh = (size_t)(b * 16 + h);
  size_t tileK = bh * 32 + n;

  { // stage Kcat rows: [0,128) from Kb, [128,256) from Ksort. chunk = 8 rows x 64 u16.
    int l8 = lane >> 3, sl8 = lane & 7;
    const u16* Korig = Kb + (bh * 4096 + (size_t)n * 128) * 64;
    const u16* Ksrt  = Ksort + tileK * 8192;
#pragma unroll
    for (int c = 0; c < 8; ++c) {
      int cc = w * 8 + c;
      int r = cc * 8 + l8;
      int pk = sl8 ^ (r & 7);
      const u16* src = (cc < 16) ? (Korig + (size_t)r * 64 + pk * 8)
                                 : (Ksrt + (size_t)(r - 128) * 64 + pk * 8);
      gll16(src, Ks + cc * 512);
    }
    // stage V panels: chunk = 4 d-rows x 128 u16.
    int l16 = lane >> 4, sl16 = lane & 15;
    const u16* Vorig = Vbt + bh * 262144 + (size_t)n * 128;
    const u16* Vsrt  = Vsort + tileK * 8192;
#pragma unroll
    for (int c = 0; c < 4; ++c) {
      int cc = w * 4 + c;
      int d = cc * 4 + l16;
      int pv = sl16 ^ (d & 15);
      gll16(Vorig + (size_t)d * 4096 + pv * 8, Vlo + cc * 512);
      gll16(Vsrt + (size_t)d * 128 + pv * 8, Vhi + cc * 512);
    }
  }

  int mm = lane & 15, quad = lane >> 4;
  bf16x8 qf[2][2];
  {
    size_t qrow = bh * 4096 + n * 128 + w * 32;
#pragma unroll
    for (int mt = 0; mt < 2; ++mt)
#pragma unroll
      for (int ks = 0; ks < 2; ++ks)
        qf[mt][ks] = *(const bf16x8*)(Qb + (qrow + mt * 16 + mm) * 64 + ks * 32 + quad * 8);
  }
  __syncthreads();

  // S = Qs @ Kcat^T  (wave w owns q rows [w*32, w*32+32))
  f32x4 S[2][16];
#pragma unroll
  for (int mt = 0; mt < 2; ++mt)
#pragma unroll
    for (int nt = 0; nt < 16; ++nt) S[mt][nt] = (f32x4){0.f, 0.f, 0.f, 0.f};
#pragma unroll
  for (int nt = 0; nt < 16; ++nt) {
    int kk = nt * 16 + mm;
#pragma unroll
    for (int ks = 0; ks < 2; ++ks) {
      int ch = (ks * 4 + quad) ^ (kk & 7);
      bf16x8 bk = *(const bf16x8*)(Ks + kk * 64 + ch * 8);
      S[0][nt] = mfma16(qf[0][ks], bk, S[0][nt]);
      S[1][nt] = mfma16(qf[1][ks], bk, S[1][nt]);
    }
  }

  // softmax over kk (C-layout: row = quad*4+r, col = mm across nt)
  float mx[2][4], ls[2][4];
#pragma unroll
  for (int mt = 0; mt < 2; ++mt)
#pragma unroll
    for (int r = 0; r < 4; ++r) {
      float v = S[mt][0][r];
#pragma unroll
      for (int nt = 1; nt < 16; ++nt) v = fmaxf(v, S[mt][nt][r]);
#pragma unroll
      for (int o = 1; o < 16; o <<= 1) v = fmaxf(v, __shfl_xor(v, o));
      mx[mt][r] = v;
    }
#pragma unroll
  for (int mt = 0; mt < 2; ++mt)
#pragma unroll
    for (int nt = 0; nt < 16; ++nt)
#pragma unroll
      for (int r = 0; r < 4; ++r)
        S[mt][nt][r] = __expf(S[mt][nt][r] - mx[mt][r]);
  float rls[2][4];
#pragma unroll
  for (int mt = 0; mt < 2; ++mt)
#pragma unroll
    for (int r = 0; r < 4; ++r) {
      float s = 0.f;
#pragma unroll
      for (int nt = 0; nt < 16; ++nt) s += S[mt][nt][r];
#pragma unroll
      for (int o = 1; o < 16; o <<= 1) s += __shfl_xor(s, o);
      ls[mt][r] = s;
      rls[mt][r] = 1.0f / s;     // hoisted: 8 divides instead of 32
    }

  __syncthreads();   // all waves done reading Ks before overlaying with P

  // PV in two kk halves; P (bf16) round-trips through per-wave LDS region over Ks
  u16* Pw = Ks + w * 4096;   // 32 q-rows x 128 kk per half (8KB per wave)
  f32x4 O[2][4];
#pragma unroll
  for (int mt = 0; mt < 2; ++mt)
#pragma unroll
    for (int dt = 0; dt < 4; ++dt) O[mt][dt] = (f32x4){0.f, 0.f, 0.f, 0.f};

#pragma unroll
  for (int half = 0; half < 2; ++half) {
    const u16* Vp = half == 0 ? Vlo : Vhi;
#pragma unroll
    for (int mt = 0; mt < 2; ++mt)
#pragma unroll
      for (int nt8 = 0; nt8 < 8; ++nt8) {
        int nt = half * 8 + nt8;
        int kkl = nt8 * 16 + mm;
#pragma unroll
        for (int r = 0; r < 4; ++r) {
          int q = mt * 16 + quad * 4 + r;
          int ch = (kkl >> 3) ^ (q & 15);
          Pw[q * 128 + ch * 8 + (kkl & 7)] = f2bf(S[mt][nt][r]);
        }
      }
#pragma unroll
    for (int ksl = 0; ksl < 4; ++ksl) {
      bf16x8 pa[2];
#pragma unroll
      for (int mt = 0; mt < 2; ++mt) {
        int q = mt * 16 + mm;
        int ch = (ksl * 4 + quad) ^ (q & 15);
        pa[mt] = *(const bf16x8*)(Pw + q * 128 + ch * 8);
      }
#pragma unroll
      for (int dt = 0; dt < 4; ++dt) {
        int d = dt * 16 + mm;
        int ch = (ksl * 4 + quad) ^ (d & 15);
        bf16x8 vb = *(const bf16x8*)(Vp + d * 128 + ch * 8);
        O[0][dt] = mfma16(pa[0], vb, O[0][dt]);
        O[1][dt] = mfma16(pa[1], vb, O[1][dt]);
      }
    }
  }

  // ---- X epilogue: per-wave LDS re-tile [32q][64d] with chunk-XOR swizzle
  //      (reuses the dead Pw region; DS ops are in-order per wave, no barrier),
  //      then 16B/lane stores: 8 lanes x 16B = full 128B row of X. ----
#pragma unroll
  for (int mt = 0; mt < 2; ++mt)
#pragma unroll
    for (int dt = 0; dt < 4; ++dt)
#pragma unroll
      for (int r = 0; r < 4; ++r) {
        int q = mt * 16 + quad * 4 + r;
        int d = dt * 16 + mm;
        int kk = (q ^ (q >> 3)) & 7;
        Pw[q * 64 + (((d >> 3) ^ kk) << 3) + (d & 7)] = f2bf(O[mt][dt][r] * rls[mt][r]);
      }
  asm volatile("s_waitcnt lgkmcnt(0)" ::: "memory");
  {
    size_t row0 = (size_t)b * 4096 + n * 128 + w * 32;
    int l8 = lane >> 3, c8 = lane & 7;
#pragma unroll
    for (int i = 0; i < 4; ++i) {
      int s = i * 8 + l8;
      int kk = (l8 ^ i) & 7;
      *(bf16x8*)(X + (row0 + s) * 1024 + h * 64 + c8 * 8) =
          *(const bf16x8*)(Pw + s * 64 + ((c8 ^ kk) << 3));
    }
  }
}

// ---------------- launch ----------------
extern "C" void kernel_launch(void* const* d_in, const int* in_sizes, int n_in,
                              void* d_out, int out_size, void* d_ws, size_t ws_size,
                              hipStream_t stream) {
  const float* inq   = (const float*)d_in[0];
  const float* wq    = (const float*)d_in[1];
  const float* bq    = (const float*)d_in[2];
  const float* wk    = (const float*)d_in[3];
  const float* bk    = (const float*)d_in[4];
  const float* wv    = (const float*)d_in[5];
  const float* bv    = (const float*)d_in[6];
  const float* wsort = (const float*)d_in[7];
  const float* bsort = (const float*)d_in[8];
  const float* wo    = (const float*)d_in[9];
  const float* bo    = (const float*)d_in[10];
  float* out = (float*)d_out;

  char* ws = (char*)d_ws;
  size_t off = 0;
  auto alloc = [&](size_t bytes) { char* p = ws + off; off += (bytes + 255) & ~(size_t)255; return p; };
  u16*  Qb    = (u16*)alloc(33554432);   // [4][16][4096][64] bf16, pre-scaled 1/8
  u16*  Kb    = (u16*)alloc(33554432);   // K [4][16][4096][64]
  u16*  Vbt   = (u16*)alloc(33554432);   // V transposed [4][16][64][4096]
  u16*  Ksort = (u16*)alloc(33554432);   // sorted K [4][16][32][128][64]
  u16*  Vsort = (u16*)alloc(33554432);   // sorted V^T [4][16][32][64][128]
  u16*  Abf   = (u16*)alloc(33554432);   // bf16 input; later aliased as X
  u16*  Wqkvt = (u16*)alloc(6291456);    // [3072][1024] bf16 (B^T)
  u16*  Wot   = (u16*)alloc(2097152);    // [1024][1024] bf16 (B^T)
  float* sumk = (float*)alloc(524288);   // [4][32][1024]
  float* perm = (float*)alloc(16384);    // [4][32][32]
  u16*  X = Abf;   // alias: attention output over Abf (dead after k_gemm_qkv)

  k_cast<<<16384, 256, 0, stream>>>(inq, Abf);
  k_transpose4<<<dim3(32, 32, 4), dim3(32, 32), 0, stream>>>(wq, wk, wv, wo, Wqkvt, Wot);
  k_gemm_qkv<<<dim3(12, 64), 512, 0, stream>>>(Abf, Wqkvt, bq, bk, bv, Qb, Kb, Vbt, sumk);
  k_sortsink<<<4, 256, 0, stream>>>(sumk, wsort, bsort, perm);
  k_mix<<<dim3(8, 32, 4), 256, 0, stream>>>(Kb, Vbt, perm, Ksort, Vsort);
  k_attn<<<dim3(32, 16, 4), 256, 0, stream>>>(Qb, Kb, Ksort, Vbt, Vsort, X);
  k_gemm_out<<<dim3(4, 64), 512, 0, stream>>>(X, Wot, bo, out);
}